// Round 1
// baseline (171.293 us; speedup 1.0000x reference)
//
#include <hip/hip_runtime.h>
#include <hip/hip_bf16.h>

#define NROWS 8192
#define KDIM  256
#define NT    64                  // NROWS / 128
#define NBLK  (NT * (NT + 1) / 2) // 2080 upper-triangular 128x128 tiles

typedef __attribute__((ext_vector_type(8))) __bf16 bf16x8;
typedef __attribute__((ext_vector_type(4))) float f32x4;

// async global->LDS, 16B per lane; LDS dest is wave-uniform base + lane*16
#define GLD(gp, lp)                                                            \
  __builtin_amdgcn_global_load_lds(                                            \
      (const __attribute__((address_space(1))) void*)(gp),                     \
      (__attribute__((address_space(3))) void*)(lp), 16, 0, 0)

// ---------------------------------------------------------------------------
// Kernel 1: fp32 -> bf16 convert + per-row sum of squares; block 0 zeroes the
// two global accumulators (stream order guarantees visibility to pair_kernel).
// ---------------------------------------------------------------------------
__global__ void prep_kernel(const float* __restrict__ samples,
                            __hip_bfloat16* __restrict__ sbf,
                            float* __restrict__ sq,
                            float* __restrict__ accg) {
  int row = blockIdx.x, t = threadIdx.x;           // 256 threads = 1 row
  size_t idx = (size_t)row * KDIM + t;
  float v = samples[idx];
  sbf[idx] = __float2bfloat16(v);
  float p = v * v;
#pragma unroll
  for (int off = 32; off; off >>= 1) p += __shfl_down(p, off);
  __shared__ float wsum[4];
  int lane = t & 63, w = t >> 6;
  if (lane == 0) wsum[w] = p;
  __syncthreads();
  if (t == 0) sq[row] = wsum[0] + wsum[1] + wsum[2] + wsum[3];
  if (row == 0 && t < 2) accg[t] = 0.0f;
}

// ---------------------------------------------------------------------------
// Kernel 2: fused Gram-tile (MFMA bf16) -> S_ij -> masked sums.
// One block = one 128x128 tile (bi<=bj). 256 threads = 4 waves, each wave a
// 64x64 quadrant as 4x4 grid of 16x16x32 MFMAs.
// ---------------------------------------------------------------------------
__global__ __launch_bounds__(256, 3) void pair_kernel(
    const __bf16* __restrict__ sbf, const float* __restrict__ sq,
    const int* __restrict__ labels, float* __restrict__ accg) {

  __shared__ __align__(16) __bf16 As[128 * 32];
  __shared__ __align__(16) __bf16 Bs[128 * 32];
  __shared__ float sqA[128], sqB[128];
  __shared__ int   laA[128], laB[128];
  __shared__ float red[8];

  int t = threadIdx.x;
  int lane = t & 63;
  int w = t >> 6;
  int wm = w >> 1, wn = w & 1;

  // decode triangular block index b -> (bi, bj), bi <= bj
  int b = blockIdx.x;
  float disc = (2.0f * NT + 1.0f) * (2.0f * NT + 1.0f) - 8.0f * (float)b;
  int bi = (int)(((2.0f * NT + 1.0f) - sqrtf(disc)) * 0.5f);
  if (bi < 0) bi = 0;
  if (bi > NT - 1) bi = NT - 1;
  while (bi > 0 && (bi * NT - bi * (bi - 1) / 2) > b) --bi;
  while (((bi + 1) * NT - (bi + 1) * bi / 2) <= b) ++bi;
  int bj = bi + (b - (bi * NT - bi * (bi - 1) / 2));

  int rowA0 = bi * 128, rowB0 = bj * 128;

  // stage sq/labels for this tile's rows and cols
  if (t < 128) { sqA[t] = sq[rowA0 + t]; laA[t] = labels[rowA0 + t]; }
  else { int u = t - 128; sqB[u] = sq[rowB0 + u]; laB[u] = labels[rowB0 + u]; }

  f32x4 acc[4][4];
#pragma unroll
  for (int i = 0; i < 4; i++)
#pragma unroll
    for (int j = 0; j < 4; j++) acc[i][j] = (f32x4){0.f, 0.f, 0.f, 0.f};

  int r = lane & 15;    // fragment row (m or n within 16)
  int ko = lane >> 4;   // k-quad: k offset = ko*8

  for (int kc = 0; kc < KDIM / 32; ++kc) {
    int kbase = kc * 32;
    __syncthreads();  // LDS reuse guard (also covers sq/label staging)
#pragma unroll
    for (int p = 0; p < 2; ++p) {
      int g = p * 256 + t;
      int m = g >> 2, cb = g & 3;
      int gc = (cb ^ ((m >> 1) & 3)) * 8;  // XOR-swizzled k-block in global
      GLD(sbf + (size_t)(rowA0 + m) * KDIM + kbase + gc, &As[p * 2048 + w * 512]);
      GLD(sbf + (size_t)(rowB0 + m) * KDIM + kbase + gc, &Bs[p * 2048 + w * 512]);
    }
    __syncthreads();

    bf16x8 af[4], bfr[4];
#pragma unroll
    for (int i = 0; i < 4; i++) {
      int m = wm * 64 + i * 16 + r;
      af[i] = *(const bf16x8*)(&As[m * 32 + ((ko ^ ((m >> 1) & 3)) * 8)]);
      int n = wn * 64 + i * 16 + r;
      bfr[i] = *(const bf16x8*)(&Bs[n * 32 + ((ko ^ ((n >> 1) & 3)) * 8)]);
    }
#pragma unroll
    for (int i = 0; i < 4; i++)
#pragma unroll
      for (int j = 0; j < 4; j++)
        acc[i][j] = __builtin_amdgcn_mfma_f32_16x16x32_bf16(af[i], bfr[j],
                                                            acc[i][j], 0, 0, 0);
  }

  // epilogue: gram -> S -> masked partial sums
  // C/D layout: col = lane&15 (n), row = (lane>>4)*4 + reg (m)
  float s1 = 0.f, s2 = 0.f;
  int q4 = (lane >> 4) * 4;
  int cl = lane & 15;
#pragma unroll
  for (int j = 0; j < 4; j++) {
    int lc = wn * 64 + j * 16 + cl;
    float sqb = sqB[lc];
    int   lb  = laB[lc];
#pragma unroll
    for (int i = 0; i < 4; i++) {
#pragma unroll
      for (int q = 0; q < 4; q++) {
        int lr = wm * 64 + i * 16 + q4 + q;
        float S = (sqA[lr] + sqb - 2.0f * acc[i][j][q]) * (1.0f / 256.0f);
        if (laA[lr] == lb) s1 += S;
        else               s2 += fmaxf(0.f, 1.f - S);
      }
    }
  }
#pragma unroll
  for (int off = 32; off; off >>= 1) {
    s1 += __shfl_down(s1, off);
    s2 += __shfl_down(s2, off);
  }
  if (lane == 0) { red[w] = s1; red[4 + w] = s2; }
  __syncthreads();
  if (t == 0) {
    float wt = (bi == bj) ? 1.0f : 2.0f;  // off-diagonal tiles count twice
    atomicAdd(&accg[0], (red[0] + red[1] + red[2] + red[3]) * wt);
    atomicAdd(&accg[1], (red[4] + red[5] + red[6] + red[7]) * wt);
  }
}

// ---------------------------------------------------------------------------
// Kernel 3: final scalar
// ---------------------------------------------------------------------------
__global__ void finalize_kernel(const float* __restrict__ accg,
                                float* __restrict__ out) {
  out[0] = 10.0f * (accg[0] + accg[1]) *
           (1.0f / ((float)NROWS * (float)NROWS));
}

extern "C" void kernel_launch(void* const* d_in, const int* in_sizes, int n_in,
                              void* d_out, int out_size, void* d_ws,
                              size_t ws_size, hipStream_t stream) {
  // inputs: 0=merged (unused), 1=input1 (unused), 2=samples, 3=labels
  const float* samples = (const float*)d_in[2];
  const int*   labels  = (const int*)d_in[3];

  char* ws = (char*)d_ws;
  __hip_bfloat16* sbf = (__hip_bfloat16*)ws;                      // 4 MiB
  float* sq   = (float*)(ws + (size_t)NROWS * KDIM * 2);          // 32 KiB
  float* accg = (float*)(ws + (size_t)NROWS * KDIM * 2 + NROWS * 4); // 8 B
  float* out  = (float*)d_out;

  prep_kernel<<<NROWS, 256, 0, stream>>>(samples, sbf, sq, accg);
  pair_kernel<<<NBLK, 256, 0, stream>>>((const __bf16*)sbf, sq, labels, accg);
  finalize_kernel<<<1, 1, 0, stream>>>(accg, out);
}